// Round 13
// baseline (77.922 us; speedup 1.0000x reference)
//
#include <hip/hip_runtime.h>
#include <hip/hip_bf16.h>
#include <math.h>

#define NSEQ 512
#define EMB 256

typedef __attribute__((ext_vector_type(8))) short bf16x8;
typedef __attribute__((ext_vector_type(4))) float f32x4;

__device__ __forceinline__ unsigned short f2bf(float f) {
    unsigned u = __float_as_uint(f);
    unsigned r = (u + 0x7FFFu + ((u >> 16) & 1u)) >> 16;
    return (unsigned short)r;
}
__device__ __forceinline__ float bf2f(unsigned short s) {
    return __uint_as_float(((unsigned)s) << 16);
}
__device__ __forceinline__ ushort4 cvt4(float4 v) {
    ushort4 o;
    o.x = f2bf(v.x); o.y = f2bf(v.y); o.z = f2bf(v.z); o.w = f2bf(v.w);
    return o;
}

// K1: projections via bf16 MFMA. A-frags built DIRECTLY from global fp32 X
// (no X LDS staging: X has zero intra-block reuse; only W is reused 4x/block).
//   blockIdx.y 0..15: seg = y>>2 (0:Q' 1:K' 2:V 3:P), wbase = (y&3)*64
//   blockIdx.y == 16: Wo fp32 -> Wob bf16 (x==0 also zeroes LN counters)
// grid (16, 17) x 256 (4 waves). LDS ~35 KB -> better occupancy than r12.
__global__ __launch_bounds__(256) void k_gemm_mfma(
    const float* __restrict__ X,
    const float* __restrict__ Wq, const float* __restrict__ Wk,
    const float* __restrict__ Wv, const float* __restrict__ Wr,
    const float* __restrict__ Wo,
    const float* __restrict__ bq, const float* __restrict__ bv,
    unsigned short* __restrict__ Qb, unsigned short* __restrict__ Kb,
    unsigned short* __restrict__ Vtb, unsigned short* __restrict__ Wob,
    float* __restrict__ maxPart,   // [2][8][256]
    unsigned* __restrict__ cnt)    // [32] LN-completion counters
{
    const int t = threadIdx.x;

    if (blockIdx.y == 16) {   // Wo fp32 -> bf16 (+ counter zeroing)
        if (blockIdx.x == 0 && t < 32) cnt[t] = 0u;
        const float4* Wg = (const float4*)Wo;
        #pragma unroll
        for (int i = 0; i < 4; ++i) {
            int idx4 = blockIdx.x * 1024 + i * 256 + t;   // 0..16383
            ((ushort4*)Wob)[idx4] = cvt4(Wg[idx4]);
        }
        return;
    }

    __shared__ __align__(16) unsigned short Ws[64 * 264];  // stride 264 bf16
    __shared__ float red[4][64];

    const int w = t >> 6, l = t & 63;
    const int ln = l & 15, kg = l >> 4;
    const int m0 = blockIdx.x * 64;
    const int nW = blockIdx.y * 64;
    const int seg = blockIdx.y >> 2;
    const int wbase = (blockIdx.y & 3) * 64;

    // A-frags direct from global fp32 (issue early; overlap with W staging)
    const int arow = (w << 4) + ln;
    const float* Xrow = X + (size_t)(m0 + arow) * 256 + kg * 8;
    bf16x8 af[8];
    #pragma unroll
    for (int ks = 0; ks < 8; ++ks) {
        float4 a0 = *(const float4*)(Xrow + ks * 32);
        float4 a1 = *(const float4*)(Xrow + ks * 32 + 4);
        ushort4 c0 = cvt4(a0), c1 = cvt4(a1);
        af[ks][0] = (short)c0.x; af[ks][1] = (short)c0.y;
        af[ks][2] = (short)c0.z; af[ks][3] = (short)c0.w;
        af[ks][4] = (short)c1.x; af[ks][5] = (short)c1.y;
        af[ks][6] = (short)c1.z; af[ks][7] = (short)c1.w;
    }

    // stage W slice (64 rows x 256 k), fused combine + cvt
    const float4* Wq4 = (const float4*)Wq;
    const float4* Wk4 = (const float4*)Wk;
    const float4* Wv4 = (const float4*)Wv;
    const float4* Wr4 = (const float4*)Wr;
    #pragma unroll
    for (int i = 0; i < 16; ++i) {
        int idx = i * 256 + t;                // float4 index 0..4095
        int row = idx >> 6, c4 = idx & 63;
        size_t off = (size_t)(wbase + row) * 64 + c4;
        float4 wv;
        if (seg == 0) {
            float4 a = Wq4[off], r = Wr4[off];
            wv = make_float4(a.x - r.x, a.y - r.y, a.z - r.z, a.w - r.w);
        } else if (seg == 1) {
            float4 a = Wk4[off], r = Wr4[off];
            wv = make_float4(a.x + r.x, a.y + r.y, a.z + r.z, a.w + r.w);
        } else if (seg == 2) {
            wv = Wv4[off];
        } else {
            wv = Wr4[off];
        }
        *(ushort4*)(Ws + row * 264 + c4 * 4) = cvt4(wv);
    }
    __syncthreads();

    f32x4 acc[4] = {{0.f,0.f,0.f,0.f},{0.f,0.f,0.f,0.f},
                    {0.f,0.f,0.f,0.f},{0.f,0.f,0.f,0.f}};
    #pragma unroll
    for (int ks = 0; ks < 8; ++ks) {
        #pragma unroll
        for (int nf = 0; nf < 4; ++nf) {
            bf16x8 b = *(const bf16x8*)(Ws + (nf * 16 + ln) * 264 + ks * 32 + kg * 8);
            acc[nf] = __builtin_amdgcn_mfma_f32_16x16x32_bf16(af[ks], b, acc[nf], 0, 0, 0);
        }
    }

    if (seg == 0) {
        #pragma unroll
        for (int nf = 0; nf < 4; ++nf) {
            int c = (nW & 255) + nf * 16 + ln;
            float bb = bq[c];
            #pragma unroll
            for (int r = 0; r < 4; ++r) {
                int row = m0 + w * 16 + kg * 4 + r;
                Qb[(size_t)row * 256 + c] = f2bf(acc[nf][r] + bb);
            }
        }
    } else if (seg == 1) {
        #pragma unroll
        for (int nf = 0; nf < 4; ++nf) {
            int c = (nW & 255) + nf * 16 + ln;
            #pragma unroll
            for (int r = 0; r < 4; ++r) {
                int row = m0 + w * 16 + kg * 4 + r;
                Kb[(size_t)row * 256 + c] = f2bf(acc[nf][r]);
            }
        }
    } else if (seg == 2) {
        #pragma unroll
        for (int nf = 0; nf < 4; ++nf) {
            int c = (nW & 255) + nf * 16 + ln;
            int h = c >> 5, d = c & 31;
            float bb = bv[c];
            #pragma unroll
            for (int r = 0; r < 4; ++r) {
                int row = m0 + w * 16 + kg * 4 + r;
                int b = row >> 9, ml = row & 511;
                Vtb[((size_t)(b * 8 + h) * 32 + d) * 512 + ml] = f2bf(acc[nf][r] + bb);
            }
        }
    } else {
        #pragma unroll
        for (int nf = 0; nf < 4; ++nf) {
            float mx = fmaxf(fmaxf(acc[nf][0], acc[nf][1]),
                             fmaxf(acc[nf][2], acc[nf][3]));
            mx = fmaxf(mx, __shfl_xor(mx, 16));
            mx = fmaxf(mx, __shfl_xor(mx, 32));
            if (l < 16) red[w][nf * 16 + ln] = mx;
        }
        __syncthreads();
        if (t < 64) {
            float m = fmaxf(fmaxf(red[0][t], red[1][t]),
                            fmaxf(red[2][t], red[3][t]));
            const int b = blockIdx.x >> 3;
            const int mblk = blockIdx.x & 7;
            maxPart[b * 2048 + mblk * 256 + (nW & 255) + t] = m;
        }
    }
}

// K2: flash attention + fused out-projection partial + LAST-BLOCK LayerNorm.
// grid (16, 8, 2) x 256. After writing its yPh plane, each block fences and
// increments cnt[bz*16+qtile]; the 8th arriver runs residual+LN1+LN2 for the
// 32 rows (fixed h-order sum -> value-deterministic).
__global__ __launch_bounds__(256) void k_attn_og(
    const unsigned short* __restrict__ Qb,   // [1024][256] bf16
    const unsigned short* __restrict__ Kb,   // [1024][256] bf16
    const unsigned short* __restrict__ Vtb,  // [16][32][512] bf16
    const unsigned short* __restrict__ Wob,  // [256][256] bf16
    const float* __restrict__ maxPart,       // [2][8][256]
    const float* __restrict__ br,
    const float* __restrict__ x, const float* __restrict__ bo,
    const float* __restrict__ g1, const float* __restrict__ b1,
    const float* __restrict__ g2, const float* __restrict__ b2,
    unsigned short* __restrict__ yPh,        // [8][1024][256] bf16
    unsigned* __restrict__ cnt,              // [32]
    float* __restrict__ out)
{
    __shared__ __align__(16) unsigned short Plds[4][32][136];
    __shared__ float Olds[4][32][33];
    __shared__ float mlds[4][32], llds[4][32];
    __shared__ float scl[4][32], Li[32];
    __shared__ float qadd[32];
    __shared__ __align__(16) unsigned short Ob[32][36];
    __shared__ float lnred[4][4][2];
    __shared__ unsigned doneOld;

    const int t = threadIdx.x;
    const int w = t >> 6, l = t & 63;
    const int ln = l & 15, kg = l >> 4;
    const int q0 = blockIdx.x * 32;
    const int h = blockIdx.y, bz = blockIdx.z;
    const int e0 = h * 32;
    const int bh = bz * 8 + h;
    const float scale = 0.17677669529663687f;  // 1/sqrt(32)

    if (t < 32) {
        float m = maxPart[bz * 2048 + e0 + t];
        #pragma unroll
        for (int j = 1; j < 8; ++j)
            m = fmaxf(m, maxPart[bz * 2048 + j * 256 + e0 + t]);
        qadd[t] = m + br[e0 + t];
    }
    __syncthreads();

    // a-frags: Qr = (Qb + maxP + br) * scale
    bf16x8 af[2];
    #pragma unroll
    for (int qf = 0; qf < 2; ++qf) {
        size_t qrow = (size_t)(bz * NSEQ + q0 + qf * 16 + ln) * 256 + e0 + kg * 8;
        bf16x8 qa = *(const bf16x8*)(Qb + qrow);
        #pragma unroll
        for (int j = 0; j < 8; ++j) {
            int d = kg * 8 + j;
            af[qf][j] = (short)f2bf((bf2f((unsigned short)qa[j]) + qadd[d]) * scale);
        }
    }

    // QK^T: 8 key-frags x 2 q-frags
    const int key0 = w * 128;
    f32x4 sc[2][8];
    #pragma unroll
    for (int kf = 0; kf < 8; ++kf) {
        size_t krow = (size_t)(bz * NSEQ + key0 + kf * 16 + ln) * 256 + e0 + kg * 8;
        bf16x8 bfr = *(const bf16x8*)(Kb + krow);
        f32x4 z = {0.f, 0.f, 0.f, 0.f};
        sc[0][kf] = __builtin_amdgcn_mfma_f32_16x16x32_bf16(af[0], bfr, z, 0, 0, 0);
        sc[1][kf] = __builtin_amdgcn_mfma_f32_16x16x32_bf16(af[1], bfr, z, 0, 0, 0);
    }

    // single-pass softmax over this wave's 128 keys; lane owns q = qf*16+kg*4+r
    float m_[2][4], l_[2][4];
    #pragma unroll
    for (int qf = 0; qf < 2; ++qf) {
        #pragma unroll
        for (int r = 0; r < 4; ++r) {
            float mx = sc[qf][0][r];
            #pragma unroll
            for (int kf = 1; kf < 8; ++kf) mx = fmaxf(mx, sc[qf][kf][r]);
            #pragma unroll
            for (int off = 1; off < 16; off <<= 1) mx = fmaxf(mx, __shfl_xor(mx, off));
            m_[qf][r] = mx;
            float s = 0.f;
            #pragma unroll
            for (int kf = 0; kf < 8; ++kf) {
                float p = __expf(sc[qf][kf][r] - mx);
                sc[qf][kf][r] = p;
                s += p;
            }
            #pragma unroll
            for (int off = 1; off < 16; off <<= 1) s += __shfl_xor(s, off);
            l_[qf][r] = s;
        }
    }

    // P -> LDS (bf16), wave-private
    #pragma unroll
    for (int qf = 0; qf < 2; ++qf)
        #pragma unroll
        for (int kf = 0; kf < 8; ++kf)
            #pragma unroll
            for (int r = 0; r < 4; ++r)
                Plds[w][qf * 16 + kg * 4 + r][kf * 16 + ln] = f2bf(sc[qf][kf][r]);

    // PV: O[32 q][32 d]
    f32x4 o[2][2] = {{{0.f,0.f,0.f,0.f},{0.f,0.f,0.f,0.f}},
                     {{0.f,0.f,0.f,0.f},{0.f,0.f,0.f,0.f}}};
    #pragma unroll
    for (int ks = 0; ks < 4; ++ks) {
        bf16x8 vf[2];
        #pragma unroll
        for (int df = 0; df < 2; ++df) {
            size_t vrow = ((size_t)bh * 32 + df * 16 + ln) * 512 + key0 + ks * 32 + kg * 8;
            vf[df] = *(const bf16x8*)(Vtb + vrow);
        }
        #pragma unroll
        for (int qf = 0; qf < 2; ++qf) {
            bf16x8 pf = *(const bf16x8*)&Plds[w][qf * 16 + ln][ks * 32 + kg * 8];
            o[qf][0] = __builtin_amdgcn_mfma_f32_16x16x32_bf16(pf, vf[0], o[qf][0], 0, 0, 0);
            o[qf][1] = __builtin_amdgcn_mfma_f32_16x16x32_bf16(pf, vf[1], o[qf][1], 0, 0, 0);
        }
    }

    // per-wave partials -> LDS
    if (ln == 0) {
        #pragma unroll
        for (int qf = 0; qf < 2; ++qf)
            #pragma unroll
            for (int r = 0; r < 4; ++r) {
                mlds[w][qf * 16 + kg * 4 + r] = m_[qf][r];
                llds[w][qf * 16 + kg * 4 + r] = l_[qf][r];
            }
    }
    #pragma unroll
    for (int qf = 0; qf < 2; ++qf)
        #pragma unroll
        for (int df = 0; df < 2; ++df)
            #pragma unroll
            for (int r = 0; r < 4; ++r)
                Olds[w][qf * 16 + kg * 4 + r][df * 16 + ln] = o[qf][df][r];
    __syncthreads();

    // combine scales per q (threads 0..31)
    if (t < 32) {
        float M = fmaxf(fmaxf(mlds[0][t], mlds[1][t]),
                        fmaxf(mlds[2][t], mlds[3][t]));
        float L = 0.f;
        #pragma unroll
        for (int wv = 0; wv < 4; ++wv) {
            float s = __expf(mlds[wv][t] - M);
            scl[wv][t] = s;
            L += s * llds[wv][t];
        }
        Li[t] = 1.f / L;
    }
    __syncthreads();

    // combine -> final O tile (bf16) in LDS
    #pragma unroll
    for (int i = 0; i < 4; ++i) {
        int idx = t + 256 * i;
        int q = idx >> 5, d = idx & 31;
        float acc = 0.f;
        #pragma unroll
        for (int wv = 0; wv < 4; ++wv)
            acc += scl[wv][q] * Olds[wv][q][d];
        Ob[q][d] = f2bf(acc * Li[q]);
    }
    __syncthreads();

    // fused out-projection partial: yPh[h] rows q0..+31, all 256 n
    bf16x8 aog[2];
    #pragma unroll
    for (int qf = 0; qf < 2; ++qf)
        aog[qf] = *(const bf16x8*)&Ob[qf * 16 + ln][kg * 8];

    unsigned short* dst = yPh + (size_t)h * (1024 * 256);
    #pragma unroll
    for (int nf = 0; nf < 4; ++nf) {
        int n = w * 64 + nf * 16 + ln;
        bf16x8 bfr = *(const bf16x8*)(Wob + (size_t)n * 256 + e0 + kg * 8);
        f32x4 z = {0.f, 0.f, 0.f, 0.f};
        f32x4 y0 = __builtin_amdgcn_mfma_f32_16x16x32_bf16(aog[0], bfr, z, 0, 0, 0);
        f32x4 y1 = __builtin_amdgcn_mfma_f32_16x16x32_bf16(aog[1], bfr, z, 0, 0, 0);
        #pragma unroll
        for (int r = 0; r < 4; ++r) {
            size_t row0 = (size_t)(bz * NSEQ + q0 + kg * 4 + r);
            dst[row0 * 256 + n] = f2bf(y0[r]);
            dst[(row0 + 16) * 256 + n] = f2bf(y1[r]);
        }
    }

    // completion protocol: release fence, count arrivals; 8th block does LN
    __threadfence();
    if (t == 0) doneOld = atomicAdd(&cnt[bz * 16 + blockIdx.x], 1u);
    __syncthreads();
    if (doneOld != 7u) return;
    __threadfence();   // acquire: other blocks' yPh writes now visible

    const int c = t;
    const int wid = t >> 6, lane = t & 63;
    for (int rg = 0; rg < 8; ++rg) {
        const size_t r0 = (size_t)(bz * NSEQ + q0 + rg * 4);
        float y[4];
        #pragma unroll
        for (int r = 0; r < 4; ++r) {
            size_t off = (r0 + r) * 256 + c;
            float acc = x[off] + bo[c];
            #pragma unroll
            for (int hh = 0; hh < 8; ++hh)
                acc += bf2f(yPh[(size_t)hh * 262144 + off]);
            y[r] = acc;
        }
        __syncthreads();
        #pragma unroll
        for (int r = 0; r < 4; ++r) {
            float s = y[r], s2 = y[r] * y[r];
            #pragma unroll
            for (int off = 32; off > 0; off >>= 1) {
                s  += __shfl_xor(s, off);
                s2 += __shfl_xor(s2, off);
            }
            if (lane == 0) { lnred[wid][r][0] = s; lnred[wid][r][1] = s2; }
        }
        __syncthreads();
        float t1[4];
        #pragma unroll
        for (int r = 0; r < 4; ++r) {
            float s  = lnred[0][r][0] + lnred[1][r][0] + lnred[2][r][0] + lnred[3][r][0];
            float s2 = lnred[0][r][1] + lnred[1][r][1] + lnred[2][r][1] + lnred[3][r][1];
            float mu = s * (1.f / 256.f);
            float var = s2 * (1.f / 256.f) - mu * mu;
            float rs = rsqrtf(var + 1e-5f);
            t1[r] = (y[r] - mu) * rs * g1[c] + b1[c];
        }
        __syncthreads();
        #pragma unroll
        for (int r = 0; r < 4; ++r) {
            float s = t1[r], s2 = t1[r] * t1[r];
            #pragma unroll
            for (int off = 32; off > 0; off >>= 1) {
                s  += __shfl_xor(s, off);
                s2 += __shfl_xor(s2, off);
            }
            if (lane == 0) { lnred[wid][r][0] = s; lnred[wid][r][1] = s2; }
        }
        __syncthreads();
        #pragma unroll
        for (int r = 0; r < 4; ++r) {
            float s  = lnred[0][r][0] + lnred[1][r][0] + lnred[2][r][0] + lnred[3][r][0];
            float s2 = lnred[0][r][1] + lnred[1][r][1] + lnred[2][r][1] + lnred[3][r][1];
            float mu = s * (1.f / 256.f);
            float var = s2 * (1.f / 256.f) - mu * mu;
            float rs = rsqrtf(var + 1e-5f);
            out[(r0 + r) * 256 + c] = (t1[r] - mu) * rs * g2[c] + b2[c];
        }
    }
}

extern "C" void kernel_launch(void* const* d_in, const int* in_sizes, int n_in,
                              void* d_out, int out_size, void* d_ws, size_t ws_size,
                              hipStream_t stream)
{
    const float* x  = (const float*)d_in[0];
    const float* Wq = (const float*)d_in[1];
    const float* bq = (const float*)d_in[2];
    const float* Wk = (const float*)d_in[3];
    const float* bk = (const float*)d_in[4];   // cancels in softmax (unused)
    const float* Wv = (const float*)d_in[5];
    const float* bv = (const float*)d_in[6];
    const float* Wr = (const float*)d_in[7];
    const float* br = (const float*)d_in[8];
    const float* Wo = (const float*)d_in[9];
    const float* bo = (const float*)d_in[10];
    const float* g1 = (const float*)d_in[11];
    const float* b1 = (const float*)d_in[12];
    const float* g2 = (const float*)d_in[13];
    const float* b2 = (const float*)d_in[14];
    float* out = (float*)d_out;
    (void)bk;

    unsigned short* u = (unsigned short*)d_ws;
    unsigned short* Qb   = u;                 // 1024*256
    unsigned short* Kb   = u + 262144;        // 1024*256
    unsigned short* Vtb  = u + 524288;        // 16*32*512
    unsigned short* Wob  = u + 786432;        // 256*256
    float* maxPart = (float*)(u + 851968);    // [2][8][256] (16 KB)
    unsigned* cnt  = (unsigned*)(u + 860160); // [32]
    unsigned short* yPh = u + 860224;         // [8][1024][256] bf16 (4 MB)

    k_gemm_mfma<<<dim3(16, 17), 256, 0, stream>>>(x, Wq, Wk, Wv, Wr, Wo, bq, bv,
                                                  Qb, Kb, Vtb, Wob, maxPart, cnt);
    k_attn_og<<<dim3(16, 8, 2), 256, 0, stream>>>(Qb, Kb, Vtb, Wob, maxPart, br,
                                                  x, bo, g1, b1, g2, b2,
                                                  yPh, cnt, out);
}

// Round 14
// 27.679 us; speedup vs baseline: 2.8153x; 2.8153x over previous
//
#include <hip/hip_runtime.h>
#include <hip/hip_bf16.h>
#include <math.h>

#define NSEQ 512
#define EMB 256

typedef __attribute__((ext_vector_type(8))) short bf16x8;
typedef __attribute__((ext_vector_type(4))) float f32x4;

__device__ __forceinline__ unsigned short f2bf(float f) {
    unsigned u = __float_as_uint(f);
    unsigned r = (u + 0x7FFFu + ((u >> 16) & 1u)) >> 16;
    return (unsigned short)r;
}
__device__ __forceinline__ float bf2f(unsigned short s) {
    return __uint_as_float(((unsigned)s) << 16);
}
__device__ __forceinline__ ushort4 cvt4(float4 v) {
    ushort4 o;
    o.x = f2bf(v.x); o.y = f2bf(v.y); o.z = f2bf(v.z); o.w = f2bf(v.w);
    return o;
}

// K1: projections via bf16 MFMA. A-frags built DIRECTLY from global fp32 X
// (no X LDS staging: X has zero intra-block reuse; only W is reused 4x/block).
//   blockIdx.y 0..15: seg = y>>2 (0:Q' 1:K' 2:V 3:P), wbase = (y&3)*64
//   blockIdx.y == 16: Wo fp32 -> Wob bf16 (piggyback)
// grid (16, 17) x 256 (4 waves). LDS ~35 KB. [r13-verified correct]
__global__ __launch_bounds__(256) void k_gemm_mfma(
    const float* __restrict__ X,
    const float* __restrict__ Wq, const float* __restrict__ Wk,
    const float* __restrict__ Wv, const float* __restrict__ Wr,
    const float* __restrict__ Wo,
    const float* __restrict__ bq, const float* __restrict__ bv,
    unsigned short* __restrict__ Qb, unsigned short* __restrict__ Kb,
    unsigned short* __restrict__ Vtb, unsigned short* __restrict__ Wob,
    float* __restrict__ maxPart)   // [2][8][256]
{
    const int t = threadIdx.x;

    if (blockIdx.y == 16) {   // Wo fp32 -> bf16
        const float4* Wg = (const float4*)Wo;
        #pragma unroll
        for (int i = 0; i < 4; ++i) {
            int idx4 = blockIdx.x * 1024 + i * 256 + t;   // 0..16383
            ((ushort4*)Wob)[idx4] = cvt4(Wg[idx4]);
        }
        return;
    }

    __shared__ __align__(16) unsigned short Ws[64 * 264];  // stride 264 bf16
    __shared__ float red[4][64];

    const int w = t >> 6, l = t & 63;
    const int ln = l & 15, kg = l >> 4;
    const int m0 = blockIdx.x * 64;
    const int nW = blockIdx.y * 64;
    const int seg = blockIdx.y >> 2;
    const int wbase = (blockIdx.y & 3) * 64;

    // A-frags direct from global fp32 (issue early; overlap with W staging)
    const int arow = (w << 4) + ln;
    const float* Xrow = X + (size_t)(m0 + arow) * 256 + kg * 8;
    bf16x8 af[8];
    #pragma unroll
    for (int ks = 0; ks < 8; ++ks) {
        float4 a0 = *(const float4*)(Xrow + ks * 32);
        float4 a1 = *(const float4*)(Xrow + ks * 32 + 4);
        ushort4 c0 = cvt4(a0), c1 = cvt4(a1);
        af[ks][0] = (short)c0.x; af[ks][1] = (short)c0.y;
        af[ks][2] = (short)c0.z; af[ks][3] = (short)c0.w;
        af[ks][4] = (short)c1.x; af[ks][5] = (short)c1.y;
        af[ks][6] = (short)c1.z; af[ks][7] = (short)c1.w;
    }

    // stage W slice (64 rows x 256 k), fused combine + cvt
    const float4* Wq4 = (const float4*)Wq;
    const float4* Wk4 = (const float4*)Wk;
    const float4* Wv4 = (const float4*)Wv;
    const float4* Wr4 = (const float4*)Wr;
    #pragma unroll
    for (int i = 0; i < 16; ++i) {
        int idx = i * 256 + t;                // float4 index 0..4095
        int row = idx >> 6, c4 = idx & 63;
        size_t off = (size_t)(wbase + row) * 64 + c4;
        float4 wv;
        if (seg == 0) {
            float4 a = Wq4[off], r = Wr4[off];
            wv = make_float4(a.x - r.x, a.y - r.y, a.z - r.z, a.w - r.w);
        } else if (seg == 1) {
            float4 a = Wk4[off], r = Wr4[off];
            wv = make_float4(a.x + r.x, a.y + r.y, a.z + r.z, a.w + r.w);
        } else if (seg == 2) {
            wv = Wv4[off];
        } else {
            wv = Wr4[off];
        }
        *(ushort4*)(Ws + row * 264 + c4 * 4) = cvt4(wv);
    }
    __syncthreads();

    f32x4 acc[4] = {{0.f,0.f,0.f,0.f},{0.f,0.f,0.f,0.f},
                    {0.f,0.f,0.f,0.f},{0.f,0.f,0.f,0.f}};
    #pragma unroll
    for (int ks = 0; ks < 8; ++ks) {
        #pragma unroll
        for (int nf = 0; nf < 4; ++nf) {
            bf16x8 b = *(const bf16x8*)(Ws + (nf * 16 + ln) * 264 + ks * 32 + kg * 8);
            acc[nf] = __builtin_amdgcn_mfma_f32_16x16x32_bf16(af[ks], b, acc[nf], 0, 0, 0);
        }
    }

    if (seg == 0) {
        #pragma unroll
        for (int nf = 0; nf < 4; ++nf) {
            int c = (nW & 255) + nf * 16 + ln;
            float bb = bq[c];
            #pragma unroll
            for (int r = 0; r < 4; ++r) {
                int row = m0 + w * 16 + kg * 4 + r;
                Qb[(size_t)row * 256 + c] = f2bf(acc[nf][r] + bb);
            }
        }
    } else if (seg == 1) {
        #pragma unroll
        for (int nf = 0; nf < 4; ++nf) {
            int c = (nW & 255) + nf * 16 + ln;
            #pragma unroll
            for (int r = 0; r < 4; ++r) {
                int row = m0 + w * 16 + kg * 4 + r;
                Kb[(size_t)row * 256 + c] = f2bf(acc[nf][r]);
            }
        }
    } else if (seg == 2) {
        #pragma unroll
        for (int nf = 0; nf < 4; ++nf) {
            int c = (nW & 255) + nf * 16 + ln;
            int h = c >> 5, d = c & 31;
            float bb = bv[c];
            #pragma unroll
            for (int r = 0; r < 4; ++r) {
                int row = m0 + w * 16 + kg * 4 + r;
                int b = row >> 9, ml = row & 511;
                Vtb[((size_t)(b * 8 + h) * 32 + d) * 512 + ml] = f2bf(acc[nf][r] + bb);
            }
        }
    } else {
        #pragma unroll
        for (int nf = 0; nf < 4; ++nf) {
            float mx = fmaxf(fmaxf(acc[nf][0], acc[nf][1]),
                             fmaxf(acc[nf][2], acc[nf][3]));
            mx = fmaxf(mx, __shfl_xor(mx, 16));
            mx = fmaxf(mx, __shfl_xor(mx, 32));
            if (l < 16) red[w][nf * 16 + ln] = mx;
        }
        __syncthreads();
        if (t < 64) {
            float m = fmaxf(fmaxf(red[0][t], red[1][t]),
                            fmaxf(red[2][t], red[3][t]));
            const int b = blockIdx.x >> 3;
            const int mblk = blockIdx.x & 7;
            maxPart[b * 2048 + mblk * 256 + (nW & 255) + t] = m;
        }
    }
}

// K2: MFMA flash attention (32-row q-tiles) + fused out-projection partial.
// grid (16, 8, 2) x 256. [r12-proven: no fences, no atomics]
__global__ __launch_bounds__(256) void k_attn_og(
    const unsigned short* __restrict__ Qb,   // [1024][256] bf16
    const unsigned short* __restrict__ Kb,   // [1024][256] bf16
    const unsigned short* __restrict__ Vtb,  // [16][32][512] bf16
    const unsigned short* __restrict__ Wob,  // [256][256] bf16
    const float* __restrict__ maxPart,       // [2][8][256]
    const float* __restrict__ br,
    unsigned short* __restrict__ yPh)        // [8][1024][256] bf16
{
    __shared__ __align__(16) unsigned short Plds[4][32][136];
    __shared__ float Olds[4][32][33];
    __shared__ float mlds[4][32], llds[4][32];
    __shared__ float scl[4][32], Li[32];
    __shared__ float qadd[32];
    __shared__ __align__(16) unsigned short Ob[32][36];

    const int t = threadIdx.x;
    const int w = t >> 6, l = t & 63;
    const int ln = l & 15, kg = l >> 4;
    const int q0 = blockIdx.x * 32;
    const int h = blockIdx.y, bz = blockIdx.z;
    const int e0 = h * 32;
    const int bh = bz * 8 + h;
    const float scale = 0.17677669529663687f;  // 1/sqrt(32)

    if (t < 32) {
        float m = maxPart[bz * 2048 + e0 + t];
        #pragma unroll
        for (int j = 1; j < 8; ++j)
            m = fmaxf(m, maxPart[bz * 2048 + j * 256 + e0 + t]);
        qadd[t] = m + br[e0 + t];
    }
    __syncthreads();

    // a-frags: Qr = (Qb + maxP + br) * scale, re-rounded to bf16
    bf16x8 af[2];
    #pragma unroll
    for (int qf = 0; qf < 2; ++qf) {
        size_t qrow = (size_t)(bz * NSEQ + q0 + qf * 16 + ln) * 256 + e0 + kg * 8;
        bf16x8 qa = *(const bf16x8*)(Qb + qrow);
        #pragma unroll
        for (int j = 0; j < 8; ++j) {
            int d = kg * 8 + j;
            af[qf][j] = (short)f2bf((bf2f((unsigned short)qa[j]) + qadd[d]) * scale);
        }
    }

    // QK^T: 8 key-frags x 2 q-frags
    const int key0 = w * 128;
    f32x4 sc[2][8];
    #pragma unroll
    for (int kf = 0; kf < 8; ++kf) {
        size_t krow = (size_t)(bz * NSEQ + key0 + kf * 16 + ln) * 256 + e0 + kg * 8;
        bf16x8 bfr = *(const bf16x8*)(Kb + krow);
        f32x4 z = {0.f, 0.f, 0.f, 0.f};
        sc[0][kf] = __builtin_amdgcn_mfma_f32_16x16x32_bf16(af[0], bfr, z, 0, 0, 0);
        sc[1][kf] = __builtin_amdgcn_mfma_f32_16x16x32_bf16(af[1], bfr, z, 0, 0, 0);
    }

    // single-pass softmax over this wave's 128 keys; lane owns q = qf*16+kg*4+r
    float m_[2][4], l_[2][4];
    #pragma unroll
    for (int qf = 0; qf < 2; ++qf) {
        #pragma unroll
        for (int r = 0; r < 4; ++r) {
            float mx = sc[qf][0][r];
            #pragma unroll
            for (int kf = 1; kf < 8; ++kf) mx = fmaxf(mx, sc[qf][kf][r]);
            #pragma unroll
            for (int off = 1; off < 16; off <<= 1) mx = fmaxf(mx, __shfl_xor(mx, off));
            m_[qf][r] = mx;
            float s = 0.f;
            #pragma unroll
            for (int kf = 0; kf < 8; ++kf) {
                float p = __expf(sc[qf][kf][r] - mx);
                sc[qf][kf][r] = p;
                s += p;
            }
            #pragma unroll
            for (int off = 1; off < 16; off <<= 1) s += __shfl_xor(s, off);
            l_[qf][r] = s;
        }
    }

    // P -> LDS (bf16), wave-private
    #pragma unroll
    for (int qf = 0; qf < 2; ++qf)
        #pragma unroll
        for (int kf = 0; kf < 8; ++kf)
            #pragma unroll
            for (int r = 0; r < 4; ++r)
                Plds[w][qf * 16 + kg * 4 + r][kf * 16 + ln] = f2bf(sc[qf][kf][r]);

    // PV: O[32 q][32 d]
    f32x4 o[2][2] = {{{0.f,0.f,0.f,0.f},{0.f,0.f,0.f,0.f}},
                     {{0.f,0.f,0.f,0.f},{0.f,0.f,0.f,0.f}}};
    #pragma unroll
    for (int ks = 0; ks < 4; ++ks) {
        bf16x8 vf[2];
        #pragma unroll
        for (int df = 0; df < 2; ++df) {
            size_t vrow = ((size_t)bh * 32 + df * 16 + ln) * 512 + key0 + ks * 32 + kg * 8;
            vf[df] = *(const bf16x8*)(Vtb + vrow);
        }
        #pragma unroll
        for (int qf = 0; qf < 2; ++qf) {
            bf16x8 pf = *(const bf16x8*)&Plds[w][qf * 16 + ln][ks * 32 + kg * 8];
            o[qf][0] = __builtin_amdgcn_mfma_f32_16x16x32_bf16(pf, vf[0], o[qf][0], 0, 0, 0);
            o[qf][1] = __builtin_amdgcn_mfma_f32_16x16x32_bf16(pf, vf[1], o[qf][1], 0, 0, 0);
        }
    }

    // per-wave partials -> LDS
    if (ln == 0) {
        #pragma unroll
        for (int qf = 0; qf < 2; ++qf)
            #pragma unroll
            for (int r = 0; r < 4; ++r) {
                mlds[w][qf * 16 + kg * 4 + r] = m_[qf][r];
                llds[w][qf * 16 + kg * 4 + r] = l_[qf][r];
            }
    }
    #pragma unroll
    for (int qf = 0; qf < 2; ++qf)
        #pragma unroll
        for (int df = 0; df < 2; ++df)
            #pragma unroll
            for (int r = 0; r < 4; ++r)
                Olds[w][qf * 16 + kg * 4 + r][df * 16 + ln] = o[qf][df][r];
    __syncthreads();

    // combine scales per q (threads 0..31)
    if (t < 32) {
        float M = fmaxf(fmaxf(mlds[0][t], mlds[1][t]),
                        fmaxf(mlds[2][t], mlds[3][t]));
        float L = 0.f;
        #pragma unroll
        for (int wv = 0; wv < 4; ++wv) {
            float s = __expf(mlds[wv][t] - M);
            scl[wv][t] = s;
            L += s * llds[wv][t];
        }
        Li[t] = 1.f / L;
    }
    __syncthreads();

    // combine -> final O tile (bf16) in LDS
    #pragma unroll
    for (int i = 0; i < 4; ++i) {
        int idx = t + 256 * i;
        int q = idx >> 5, d = idx & 31;
        float acc = 0.f;
        #pragma unroll
        for (int wv = 0; wv < 4; ++wv)
            acc += scl[wv][q] * Olds[wv][q][d];
        Ob[q][d] = f2bf(acc * Li[q]);
    }
    __syncthreads();

    // fused out-projection partial: yPh[h][rows][n] = O(32xK32) @ Wob[n][e0..+31]
    bf16x8 aog[2];
    #pragma unroll
    for (int qf = 0; qf < 2; ++qf)
        aog[qf] = *(const bf16x8*)&Ob[qf * 16 + ln][kg * 8];

    unsigned short* dst = yPh + (size_t)h * (1024 * 256);
    #pragma unroll
    for (int nf = 0; nf < 4; ++nf) {
        int n = w * 64 + nf * 16 + ln;
        bf16x8 bfr = *(const bf16x8*)(Wob + (size_t)n * 256 + e0 + kg * 8);
        f32x4 z = {0.f, 0.f, 0.f, 0.f};
        f32x4 y0 = __builtin_amdgcn_mfma_f32_16x16x32_bf16(aog[0], bfr, z, 0, 0, 0);
        f32x4 y1 = __builtin_amdgcn_mfma_f32_16x16x32_bf16(aog[1], bfr, z, 0, 0, 0);
        #pragma unroll
        for (int r = 0; r < 4; ++r) {
            size_t row0 = (size_t)(bz * NSEQ + q0 + kg * 4 + r);
            dst[row0 * 256 + n] = f2bf(y0[r]);
            dst[(row0 + 16) * 256 + n] = f2bf(y1[r]);
        }
    }
}

// K3: y = x + bo + sum_h yPh ; LN1 ; LN2. grid 256 x 256; 4 rows/block.
__global__ __launch_bounds__(256) void k_lnorm(
    const unsigned short* __restrict__ yPh, const float* __restrict__ x,
    const float* __restrict__ bo,
    const float* __restrict__ g1, const float* __restrict__ b1,
    const float* __restrict__ g2, const float* __restrict__ b2,
    float* __restrict__ out)
{
    __shared__ float red[4][4][2];
    const int t = threadIdx.x;
    const int r0 = blockIdx.x * 4;
    const int c = t;
    const int wid = t >> 6, lane = t & 63;

    float y[4];
    #pragma unroll
    for (int r = 0; r < 4; ++r) {
        size_t off = (size_t)(r0 + r) * 256 + c;
        float acc = x[off] + bo[c];
        #pragma unroll
        for (int h = 0; h < 8; ++h)
            acc += bf2f(yPh[(size_t)h * 262144 + off]);
        y[r] = acc;
    }

    // LN1
    #pragma unroll
    for (int r = 0; r < 4; ++r) {
        float s = y[r], s2 = y[r] * y[r];
        #pragma unroll
        for (int off = 32; off > 0; off >>= 1) {
            s  += __shfl_xor(s, off);
            s2 += __shfl_xor(s2, off);
        }
        if (lane == 0) { red[wid][r][0] = s; red[wid][r][1] = s2; }
    }
    __syncthreads();
    float t1[4];
    #pragma unroll
    for (int r = 0; r < 4; ++r) {
        float s  = red[0][r][0] + red[1][r][0] + red[2][r][0] + red[3][r][0];
        float s2 = red[0][r][1] + red[1][r][1] + red[2][r][1] + red[3][r][1];
        float mu = s * (1.f / 256.f);
        float var = s2 * (1.f / 256.f) - mu * mu;
        float rs = rsqrtf(var + 1e-5f);
        t1[r] = (y[r] - mu) * rs * g1[c] + b1[c];
    }
    __syncthreads();

    // LN2
    #pragma unroll
    for (int r = 0; r < 4; ++r) {
        float s = t1[r], s2 = t1[r] * t1[r];
        #pragma unroll
        for (int off = 32; off > 0; off >>= 1) {
            s  += __shfl_xor(s, off);
            s2 += __shfl_xor(s2, off);
        }
        if (lane == 0) { red[wid][r][0] = s; red[wid][r][1] = s2; }
    }
    __syncthreads();
    #pragma unroll
    for (int r = 0; r < 4; ++r) {
        float s  = red[0][r][0] + red[1][r][0] + red[2][r][0] + red[3][r][0];
        float s2 = red[0][r][1] + red[1][r][1] + red[2][r][1] + red[3][r][1];
        float mu = s * (1.f / 256.f);
        float var = s2 * (1.f / 256.f) - mu * mu;
        float rs = rsqrtf(var + 1e-5f);
        out[(size_t)(r0 + r) * 256 + c] = (t1[r] - mu) * rs * g2[c] + b2[c];
    }
}

extern "C" void kernel_launch(void* const* d_in, const int* in_sizes, int n_in,
                              void* d_out, int out_size, void* d_ws, size_t ws_size,
                              hipStream_t stream)
{
    const float* x  = (const float*)d_in[0];
    const float* Wq = (const float*)d_in[1];
    const float* bq = (const float*)d_in[2];
    const float* Wk = (const float*)d_in[3];
    const float* bk = (const float*)d_in[4];   // cancels in softmax (unused)
    const float* Wv = (const float*)d_in[5];
    const float* bv = (const float*)d_in[6];
    const float* Wr = (const float*)d_in[7];
    const float* br = (const float*)d_in[8];
    const float* Wo = (const float*)d_in[9];
    const float* bo = (const float*)d_in[10];
    const float* g1 = (const float*)d_in[11];
    const float* b1 = (const float*)d_in[12];
    const float* g2 = (const float*)d_in[13];
    const float* b2 = (const float*)d_in[14];
    float* out = (float*)d_out;
    (void)bk;

    unsigned short* u = (unsigned short*)d_ws;
    unsigned short* Qb   = u;                 // 1024*256
    unsigned short* Kb   = u + 262144;        // 1024*256
    unsigned short* Vtb  = u + 524288;        // 16*32*512
    unsigned short* Wob  = u + 786432;        // 256*256
    float* maxPart = (float*)(u + 851968);    // [2][8][256] (16 KB)
    unsigned short* yPh = u + 860160;         // [8][1024][256] bf16 (4 MB)

    k_gemm_mfma<<<dim3(16, 17), 256, 0, stream>>>(x, Wq, Wk, Wv, Wr, Wo, bq, bv,
                                                  Qb, Kb, Vtb, Wob, maxPart);
    k_attn_og<<<dim3(16, 8, 2), 256, 0, stream>>>(Qb, Kb, Vtb, Wob, maxPart,
                                                  br, yPh);
    k_lnorm<<<256, 256, 0, stream>>>(yPh, x, bo, g1, b1, g2, b2, out);
}

// Round 15
// 26.532 us; speedup vs baseline: 2.9369x; 1.0432x over previous
//
#include <hip/hip_runtime.h>
#include <hip/hip_bf16.h>
#include <math.h>

#define NSEQ 512
#define EMB 256

typedef __attribute__((ext_vector_type(8))) short bf16x8;
typedef __attribute__((ext_vector_type(4))) float f32x4;

__device__ __forceinline__ unsigned short f2bf(float f) {
    unsigned u = __float_as_uint(f);
    unsigned r = (u + 0x7FFFu + ((u >> 16) & 1u)) >> 16;
    return (unsigned short)r;
}
__device__ __forceinline__ float bf2f(unsigned short s) {
    return __uint_as_float(((unsigned)s) << 16);
}
__device__ __forceinline__ ushort4 cvt4(float4 v) {
    ushort4 o;
    o.x = f2bf(v.x); o.y = f2bf(v.y); o.z = f2bf(v.z); o.w = f2bf(v.w);
    return o;
}

// K1: projections via bf16 MFMA. A-frags direct from global fp32 X.
//   blockIdx.y 0..15: seg = y>>2 (0:Q' 1:K' 2:V 3:P), wbase = (y&3)*64
//   Wo fp32->bf16 cvt folded into the 64 seg3 blocks (1 ushort4/thread).
// grid (16, 16) x 256 (4 waves). LDS ~35 KB.
__global__ __launch_bounds__(256) void k_gemm_mfma(
    const float* __restrict__ X,
    const float* __restrict__ Wq, const float* __restrict__ Wk,
    const float* __restrict__ Wv, const float* __restrict__ Wr,
    const float* __restrict__ Wo,
    const float* __restrict__ bq, const float* __restrict__ bv,
    unsigned short* __restrict__ Qb, unsigned short* __restrict__ Kb,
    unsigned short* __restrict__ Vtb, unsigned short* __restrict__ Wob,
    float* __restrict__ maxPart)   // [2][8][256]
{
    __shared__ __align__(16) unsigned short Ws[64 * 264];  // stride 264 bf16
    __shared__ float red[4][64];

    const int t = threadIdx.x;
    const int w = t >> 6, l = t & 63;
    const int ln = l & 15, kg = l >> 4;
    const int m0 = blockIdx.x * 64;
    const int nW = blockIdx.y * 64;
    const int seg = blockIdx.y >> 2;
    const int wbase = (blockIdx.y & 3) * 64;

    // piggyback: seg3 blocks convert Wo (64 blocks x 256 ushort4 = whole Wo)
    if (seg == 3) {
        int bidL = (blockIdx.y & 3) * 16 + blockIdx.x;     // 0..63
        int idx4 = bidL * 256 + t;                          // 0..16383
        ((ushort4*)Wob)[idx4] = cvt4(((const float4*)Wo)[idx4]);
    }

    // A-frags direct from global fp32 (issue early; overlap with W staging)
    const int arow = (w << 4) + ln;
    const float* Xrow = X + (size_t)(m0 + arow) * 256 + kg * 8;
    bf16x8 af[8];
    #pragma unroll
    for (int ks = 0; ks < 8; ++ks) {
        float4 a0 = *(const float4*)(Xrow + ks * 32);
        float4 a1 = *(const float4*)(Xrow + ks * 32 + 4);
        ushort4 c0 = cvt4(a0), c1 = cvt4(a1);
        af[ks][0] = (short)c0.x; af[ks][1] = (short)c0.y;
        af[ks][2] = (short)c0.z; af[ks][3] = (short)c0.w;
        af[ks][4] = (short)c1.x; af[ks][5] = (short)c1.y;
        af[ks][6] = (short)c1.z; af[ks][7] = (short)c1.w;
    }

    // stage W slice (64 rows x 256 k), fused combine + cvt
    const float4* Wq4 = (const float4*)Wq;
    const float4* Wk4 = (const float4*)Wk;
    const float4* Wv4 = (const float4*)Wv;
    const float4* Wr4 = (const float4*)Wr;
    #pragma unroll
    for (int i = 0; i < 16; ++i) {
        int idx = i * 256 + t;                // float4 index 0..4095
        int row = idx >> 6, c4 = idx & 63;
        size_t off = (size_t)(wbase + row) * 64 + c4;
        float4 wv;
        if (seg == 0) {
            float4 a = Wq4[off], r = Wr4[off];
            wv = make_float4(a.x - r.x, a.y - r.y, a.z - r.z, a.w - r.w);
        } else if (seg == 1) {
            float4 a = Wk4[off], r = Wr4[off];
            wv = make_float4(a.x + r.x, a.y + r.y, a.z + r.z, a.w + r.w);
        } else if (seg == 2) {
            wv = Wv4[off];
        } else {
            wv = Wr4[off];
        }
        *(ushort4*)(Ws + row * 264 + c4 * 4) = cvt4(wv);
    }
    __syncthreads();

    f32x4 acc[4] = {{0.f,0.f,0.f,0.f},{0.f,0.f,0.f,0.f},
                    {0.f,0.f,0.f,0.f},{0.f,0.f,0.f,0.f}};
    #pragma unroll
    for (int ks = 0; ks < 8; ++ks) {
        #pragma unroll
        for (int nf = 0; nf < 4; ++nf) {
            bf16x8 b = *(const bf16x8*)(Ws + (nf * 16 + ln) * 264 + ks * 32 + kg * 8);
            acc[nf] = __builtin_amdgcn_mfma_f32_16x16x32_bf16(af[ks], b, acc[nf], 0, 0, 0);
        }
    }

    if (seg == 0) {
        #pragma unroll
        for (int nf = 0; nf < 4; ++nf) {
            int c = (nW & 255) + nf * 16 + ln;
            float bb = bq[c];
            #pragma unroll
            for (int r = 0; r < 4; ++r) {
                int row = m0 + w * 16 + kg * 4 + r;
                Qb[(size_t)row * 256 + c] = f2bf(acc[nf][r] + bb);
            }
        }
    } else if (seg == 1) {
        #pragma unroll
        for (int nf = 0; nf < 4; ++nf) {
            int c = (nW & 255) + nf * 16 + ln;
            #pragma unroll
            for (int r = 0; r < 4; ++r) {
                int row = m0 + w * 16 + kg * 4 + r;
                Kb[(size_t)row * 256 + c] = f2bf(acc[nf][r]);
            }
        }
    } else if (seg == 2) {
        #pragma unroll
        for (int nf = 0; nf < 4; ++nf) {
            int c = (nW & 255) + nf * 16 + ln;
            int h = c >> 5, d = c & 31;
            float bb = bv[c];
            #pragma unroll
            for (int r = 0; r < 4; ++r) {
                int row = m0 + w * 16 + kg * 4 + r;
                int b = row >> 9, ml = row & 511;
                Vtb[((size_t)(b * 8 + h) * 32 + d) * 512 + ml] = f2bf(acc[nf][r] + bb);
            }
        }
    } else {
        #pragma unroll
        for (int nf = 0; nf < 4; ++nf) {
            float mx = fmaxf(fmaxf(acc[nf][0], acc[nf][1]),
                             fmaxf(acc[nf][2], acc[nf][3]));
            mx = fmaxf(mx, __shfl_xor(mx, 16));
            mx = fmaxf(mx, __shfl_xor(mx, 32));
            if (l < 16) red[w][nf * 16 + ln] = mx;
        }
        __syncthreads();
        if (t < 64) {
            float m = fmaxf(fmaxf(red[0][t], red[1][t]),
                            fmaxf(red[2][t], red[3][t]));
            const int b = blockIdx.x >> 3;
            const int mblk = blockIdx.x & 7;
            maxPart[b * 2048 + mblk * 256 + (nW & 255) + t] = m;
        }
    }
}

// K2: MFMA flash attention (32-row q-tiles) + fused out-projection partial.
// grid (16, 8, 2) x 256. [r12/r14-proven: no fences, no atomics]
__global__ __launch_bounds__(256) void k_attn_og(
    const unsigned short* __restrict__ Qb,   // [1024][256] bf16
    const unsigned short* __restrict__ Kb,   // [1024][256] bf16
    const unsigned short* __restrict__ Vtb,  // [16][32][512] bf16
    const unsigned short* __restrict__ Wob,  // [256][256] bf16
    const float* __restrict__ maxPart,       // [2][8][256]
    const float* __restrict__ br,
    unsigned short* __restrict__ yPh)        // [8][1024][256] bf16
{
    __shared__ __align__(16) unsigned short Plds[4][32][136];
    __shared__ float Olds[4][32][33];
    __shared__ float mlds[4][32], llds[4][32];
    __shared__ float scl[4][32], Li[32];
    __shared__ float qadd[32];
    __shared__ __align__(16) unsigned short Ob[32][36];

    const int t = threadIdx.x;
    const int w = t >> 6, l = t & 63;
    const int ln = l & 15, kg = l >> 4;
    const int q0 = blockIdx.x * 32;
    const int h = blockIdx.y, bz = blockIdx.z;
    const int e0 = h * 32;
    const int bh = bz * 8 + h;
    const float scale = 0.17677669529663687f;  // 1/sqrt(32)

    if (t < 32) {
        float m = maxPart[bz * 2048 + e0 + t];
        #pragma unroll
        for (int j = 1; j < 8; ++j)
            m = fmaxf(m, maxPart[bz * 2048 + j * 256 + e0 + t]);
        qadd[t] = m + br[e0 + t];
    }
    __syncthreads();

    // a-frags: Qr = (Qb + maxP + br) * scale, re-rounded to bf16
    bf16x8 af[2];
    #pragma unroll
    for (int qf = 0; qf < 2; ++qf) {
        size_t qrow = (size_t)(bz * NSEQ + q0 + qf * 16 + ln) * 256 + e0 + kg * 8;
        bf16x8 qa = *(const bf16x8*)(Qb + qrow);
        #pragma unroll
        for (int j = 0; j < 8; ++j) {
            int d = kg * 8 + j;
            af[qf][j] = (short)f2bf((bf2f((unsigned short)qa[j]) + qadd[d]) * scale);
        }
    }

    // QK^T: 8 key-frags x 2 q-frags
    const int key0 = w * 128;
    f32x4 sc[2][8];
    #pragma unroll
    for (int kf = 0; kf < 8; ++kf) {
        size_t krow = (size_t)(bz * NSEQ + key0 + kf * 16 + ln) * 256 + e0 + kg * 8;
        bf16x8 bfr = *(const bf16x8*)(Kb + krow);
        f32x4 z = {0.f, 0.f, 0.f, 0.f};
        sc[0][kf] = __builtin_amdgcn_mfma_f32_16x16x32_bf16(af[0], bfr, z, 0, 0, 0);
        sc[1][kf] = __builtin_amdgcn_mfma_f32_16x16x32_bf16(af[1], bfr, z, 0, 0, 0);
    }

    // single-pass softmax over this wave's 128 keys; lane owns q = qf*16+kg*4+r
    float m_[2][4], l_[2][4];
    #pragma unroll
    for (int qf = 0; qf < 2; ++qf) {
        #pragma unroll
        for (int r = 0; r < 4; ++r) {
            float mx = sc[qf][0][r];
            #pragma unroll
            for (int kf = 1; kf < 8; ++kf) mx = fmaxf(mx, sc[qf][kf][r]);
            #pragma unroll
            for (int off = 1; off < 16; off <<= 1) mx = fmaxf(mx, __shfl_xor(mx, off));
            m_[qf][r] = mx;
            float s = 0.f;
            #pragma unroll
            for (int kf = 0; kf < 8; ++kf) {
                float p = __expf(sc[qf][kf][r] - mx);
                sc[qf][kf][r] = p;
                s += p;
            }
            #pragma unroll
            for (int off = 1; off < 16; off <<= 1) s += __shfl_xor(s, off);
            l_[qf][r] = s;
        }
    }

    // P -> LDS (bf16), wave-private
    #pragma unroll
    for (int qf = 0; qf < 2; ++qf)
        #pragma unroll
        for (int kf = 0; kf < 8; ++kf)
            #pragma unroll
            for (int r = 0; r < 4; ++r)
                Plds[w][qf * 16 + kg * 4 + r][kf * 16 + ln] = f2bf(sc[qf][kf][r]);

    // PV: O[32 q][32 d]
    f32x4 o[2][2] = {{{0.f,0.f,0.f,0.f},{0.f,0.f,0.f,0.f}},
                     {{0.f,0.f,0.f,0.f},{0.f,0.f,0.f,0.f}}};
    #pragma unroll
    for (int ks = 0; ks < 4; ++ks) {
        bf16x8 vf[2];
        #pragma unroll
        for (int df = 0; df < 2; ++df) {
            size_t vrow = ((size_t)bh * 32 + df * 16 + ln) * 512 + key0 + ks * 32 + kg * 8;
            vf[df] = *(const bf16x8*)(Vtb + vrow);
        }
        #pragma unroll
        for (int qf = 0; qf < 2; ++qf) {
            bf16x8 pf = *(const bf16x8*)&Plds[w][qf * 16 + ln][ks * 32 + kg * 8];
            o[qf][0] = __builtin_amdgcn_mfma_f32_16x16x32_bf16(pf, vf[0], o[qf][0], 0, 0, 0);
            o[qf][1] = __builtin_amdgcn_mfma_f32_16x16x32_bf16(pf, vf[1], o[qf][1], 0, 0, 0);
        }
    }

    // per-wave partials -> LDS
    if (ln == 0) {
        #pragma unroll
        for (int qf = 0; qf < 2; ++qf)
            #pragma unroll
            for (int r = 0; r < 4; ++r) {
                mlds[w][qf * 16 + kg * 4 + r] = m_[qf][r];
                llds[w][qf * 16 + kg * 4 + r] = l_[qf][r];
            }
    }
    #pragma unroll
    for (int qf = 0; qf < 2; ++qf)
        #pragma unroll
        for (int df = 0; df < 2; ++df)
            #pragma unroll
            for (int r = 0; r < 4; ++r)
                Olds[w][qf * 16 + kg * 4 + r][df * 16 + ln] = o[qf][df][r];
    __syncthreads();

    // combine scales per q (threads 0..31)
    if (t < 32) {
        float M = fmaxf(fmaxf(mlds[0][t], mlds[1][t]),
                        fmaxf(mlds[2][t], mlds[3][t]));
        float L = 0.f;
        #pragma unroll
        for (int wv = 0; wv < 4; ++wv) {
            float s = __expf(mlds[wv][t] - M);
            scl[wv][t] = s;
            L += s * llds[wv][t];
        }
        Li[t] = 1.f / L;
    }
    __syncthreads();

    // combine -> final O tile (bf16) in LDS
    #pragma unroll
    for (int i = 0; i < 4; ++i) {
        int idx = t + 256 * i;
        int q = idx >> 5, d = idx & 31;
        float acc = 0.f;
        #pragma unroll
        for (int wv = 0; wv < 4; ++wv)
            acc += scl[wv][q] * Olds[wv][q][d];
        Ob[q][d] = f2bf(acc * Li[q]);
    }
    __syncthreads();

    // fused out-projection partial: yPh[h][rows][n] = O(32xK32) @ Wob[n][e0..+31]
    bf16x8 aog[2];
    #pragma unroll
    for (int qf = 0; qf < 2; ++qf)
        aog[qf] = *(const bf16x8*)&Ob[qf * 16 + ln][kg * 8];

    unsigned short* dst = yPh + (size_t)h * (1024 * 256);
    #pragma unroll
    for (int nf = 0; nf < 4; ++nf) {
        int n = w * 64 + nf * 16 + ln;
        bf16x8 bfr = *(const bf16x8*)(Wob + (size_t)n * 256 + e0 + kg * 8);
        f32x4 z = {0.f, 0.f, 0.f, 0.f};
        f32x4 y0 = __builtin_amdgcn_mfma_f32_16x16x32_bf16(aog[0], bfr, z, 0, 0, 0);
        f32x4 y1 = __builtin_amdgcn_mfma_f32_16x16x32_bf16(aog[1], bfr, z, 0, 0, 0);
        #pragma unroll
        for (int r = 0; r < 4; ++r) {
            size_t row0 = (size_t)(bz * NSEQ + q0 + kg * 4 + r);
            dst[row0 * 256 + n] = f2bf(y0[r]);
            dst[(row0 + 16) * 256 + n] = f2bf(y1[r]);
        }
    }
}

// K3: y = x + bo + sum_h yPh ; LN1 ; LN2. grid 256 x 256.
// Vectorized: thread = (row-pair rp, channel-pair c2); uint plane loads,
// float2 x/param loads, float2 stores (G13: no scalar bf16 loads).
__global__ __launch_bounds__(256) void k_lnorm(
    const unsigned short* __restrict__ yPh, const float* __restrict__ x,
    const float* __restrict__ bo,
    const float* __restrict__ g1, const float* __restrict__ b1,
    const float* __restrict__ g2, const float* __restrict__ b2,
    float* __restrict__ out)
{
    __shared__ float red[4][2][2];   // [wave][row-in-pair][{s,s2}]
    const int t = threadIdx.x;
    const int r0 = blockIdx.x * 4;
    const int rp = t >> 7;           // row-pair: rows r0+2rp, r0+2rp+1
    const int c0 = (t & 127) * 2;    // channel pair
    const int wv = t >> 6;

    const float2 bo2 = *(const float2*)(bo + c0);
    const float2 g12 = *(const float2*)(g1 + c0);
    const float2 b12 = *(const float2*)(b1 + c0);
    const float2 g22 = *(const float2*)(g2 + c0);
    const float2 b22 = *(const float2*)(b2 + c0);

    float a[2][2];
    #pragma unroll
    for (int rr = 0; rr < 2; ++rr) {
        size_t off = (size_t)(r0 + rp * 2 + rr) * 256 + c0;
        float2 xv = *(const float2*)(x + off);
        float a0 = xv.x + bo2.x, a1 = xv.y + bo2.y;
        #pragma unroll
        for (int h = 0; h < 8; ++h) {
            unsigned u = *(const unsigned*)(yPh + (size_t)h * 262144 + off);
            a0 += bf2f((unsigned short)(u & 0xffffu));
            a1 += bf2f((unsigned short)(u >> 16));
        }
        a[rr][0] = a0; a[rr][1] = a1;
    }

    // LN1 reduction: per-wave shfl, then combine 2 waves of this rp group
    float mu[2], rs[2];
    {
        float s[2], s2[2];
        #pragma unroll
        for (int rr = 0; rr < 2; ++rr) {
            s[rr]  = a[rr][0] + a[rr][1];
            s2[rr] = a[rr][0] * a[rr][0] + a[rr][1] * a[rr][1];
            #pragma unroll
            for (int off = 1; off < 64; off <<= 1) {
                s[rr]  += __shfl_xor(s[rr], off);
                s2[rr] += __shfl_xor(s2[rr], off);
            }
        }
        if ((t & 63) == 0) {
            #pragma unroll
            for (int rr = 0; rr < 2; ++rr) {
                red[wv][rr][0] = s[rr];
                red[wv][rr][1] = s2[rr];
            }
        }
        __syncthreads();
        #pragma unroll
        for (int rr = 0; rr < 2; ++rr) {
            float S  = red[rp * 2][rr][0] + red[rp * 2 + 1][rr][0];
            float S2 = red[rp * 2][rr][1] + red[rp * 2 + 1][rr][1];
            mu[rr] = S * (1.f / 256.f);
            float var = S2 * (1.f / 256.f) - mu[rr] * mu[rr];
            rs[rr] = rsqrtf(var + 1e-5f);
        }
    }

    float t1[2][2];
    #pragma unroll
    for (int rr = 0; rr < 2; ++rr) {
        t1[rr][0] = (a[rr][0] - mu[rr]) * rs[rr] * g12.x + b12.x;
        t1[rr][1] = (a[rr][1] - mu[rr]) * rs[rr] * g12.y + b12.y;
    }
    __syncthreads();   // red reuse guard

    // LN2 reduction
    {
        float s[2], s2[2];
        #pragma unroll
        for (int rr = 0; rr < 2; ++rr) {
            s[rr]  = t1[rr][0] + t1[rr][1];
            s2[rr] = t1[rr][0] * t1[rr][0] + t1[rr][1] * t1[rr][1];
            #pragma unroll
            for (int off = 1; off < 64; off <<= 1) {
                s[rr]  += __shfl_xor(s[rr], off);
                s2[rr] += __shfl_xor(s2[rr], off);
            }
        }
        if ((t & 63) == 0) {
            #pragma unroll
            for (int rr = 0; rr < 2; ++rr) {
                red[wv][rr][0] = s[rr];
                red[wv][rr][1] = s2[rr];
            }
        }
        __syncthreads();
        #pragma unroll
        for (int rr = 0; rr < 2; ++rr) {
            float S  = red[rp * 2][rr][0] + red[rp * 2 + 1][rr][0];
            float S2 = red[rp * 2][rr][1] + red[rp * 2 + 1][rr][1];
            float m2 = S * (1.f / 256.f);
            float var = S2 * (1.f / 256.f) - m2 * m2;
            float r2 = rsqrtf(var + 1e-5f);
            size_t off = (size_t)(r0 + rp * 2 + rr) * 256 + c0;
            float2 o;
            o.x = (t1[rr][0] - m2) * r2 * g22.x + b22.x;
            o.y = (t1[rr][1] - m2) * r2 * g22.y + b22.y;
            *(float2*)(out + off) = o;
        }
    }
}

extern "C" void kernel_launch(void* const* d_in, const int* in_sizes, int n_in,
                              void* d_out, int out_size, void* d_ws, size_t ws_size,
                              hipStream_t stream)
{
    const float* x  = (const float*)d_in[0];
    const float* Wq = (const float*)d_in[1];
    const float* bq = (const float*)d_in[2];
    const float* Wk = (const float*)d_in[3];
    const float* bk = (const float*)d_in[4];   // cancels in softmax (unused)
    const float* Wv = (const float*)d_in[5];
    const float* bv = (const float*)d_in[6];
    const float* Wr = (const float*)d_in[7];
    const float* br = (const float*)d_in[8];
    const float* Wo = (const float*)d_in[9];
    const float* bo = (const float*)d_in[10];
    const float* g1 = (const float*)d_in[11];
    const float* b1 = (const float*)d_in[12];
    const float* g2 = (const float*)d_in[13];
    const float* b2 = (const float*)d_in[14];
    float* out = (float*)d_out;
    (void)bk;

    unsigned short* u = (unsigned short*)d_ws;
    unsigned short* Qb   = u;                 // 1024*256
    unsigned short* Kb   = u + 262144;        // 1024*256
    unsigned short* Vtb  = u + 524288;        // 16*32*512
    unsigned short* Wob  = u + 786432;        // 256*256
    float* maxPart = (float*)(u + 851968);    // [2][8][256] (16 KB)
    unsigned short* yPh = u + 860160;         // [8][1024][256] bf16 (4 MB)

    k_gemm_mfma<<<dim3(16, 16), 256, 0, stream>>>(x, Wq, Wk, Wv, Wr, Wo, bq, bv,
                                                  Qb, Kb, Vtb, Wob, maxPart);
    k_attn_og<<<dim3(16, 8, 2), 256, 0, stream>>>(Qb, Kb, Vtb, Wob, maxPart,
                                                  br, yPh);
    k_lnorm<<<256, 256, 0, stream>>>(yPh, x, bo, g1, b1, g2, b2, out);
}